// Round 12
// baseline (59.594 us; speedup 1.0000x reference)
//
#include <hip/hip_runtime.h>

// ResidualVQ forward: out[n] = codebook[argmin_k(-2 x.c_k + ||c_k||^2)]
// v12: hand-pipelined K-loop. Prefetch via volatile inline-asm
// global_load_dwordx4 (compiler cannot sink it) + counted s_waitcnt vmcnt(8)
// + sched_barrier(0) before each MFMA cluster (T3/T4 recipe). rf=2 (32 rows
// per wave per fragment load, halves L2 traffic), single-term bf16 GEMM
// (|dist err| <= ~2.0 < MARGIN, exact fp32 recheck restores correctness).

typedef short bfrag __attribute__((ext_vector_type(8)));  // 8 bf16 = 4 VGPR
typedef float f32x4 __attribute__((ext_vector_type(4)));

constexpr int D = 128;      // embedding dim
constexpr int BR = 64;      // rows per block -> grid 512 = 2 blocks/CU
constexpr int NTH = 256;    // 4 waves: 2 row-groups (32 rows) x 2 K-halves
constexpr int LCAP = 2048;  // candidate capacity per block (expect ~500)
#define MARGIN 3.25f        // > 2 * max |approx dist err| (pure-bf16 bound ~2.0)

__device__ __forceinline__ unsigned fenc(float f) {  // order-preserving f32->u32
    unsigned u = __float_as_uint(f);
    return (u & 0x80000000u) ? ~u : (u | 0x80000000u);
}
__device__ __forceinline__ unsigned cvtpk(float a, float b) {
    unsigned r;
    asm("v_cvt_pk_bf16_f32 %0, %1, %2" : "=v"(r) : "v"(a), "v"(b));
    return r;
}
union FU { bfrag v; unsigned u[4]; };

// --- prep: exact cnorm (K threads) + bf16 fragment cast (K*16 threads) ---
// Fragment t (= cg*256 + ks*64 + lane, lane=kg*16+la) holds
// cb[cg*16+la][ks*32+kg*8 .. +7], bf16 RN. Coalesced 16B writes.
__global__ __launch_bounds__(256) void prep_kernel(const float* __restrict__ cb,
                                                   float* __restrict__ cnorm,
                                                   short* __restrict__ hi, int K) {
    const int tg = blockIdx.x * 256 + threadIdx.x;  // 0..16383
    {
        const int cg = tg >> 8;
        const int r = tg & 255;
        const int ks = r >> 6;
        const int lane = r & 63;
        const int kg = lane >> 4, la = lane & 15;
        const float* src = cb + (size_t)(cg * 16 + la) * D + ks * 32 + kg * 8;
        float4 f0 = *(const float4*)src;
        float4 f1 = *(const float4*)(src + 4);
        FU h;
        h.u[0] = cvtpk(f0.x, f0.y);
        h.u[1] = cvtpk(f0.z, f0.w);
        h.u[2] = cvtpk(f1.x, f1.y);
        h.u[3] = cvtpk(f1.z, f1.w);
        ((bfrag*)hi)[tg] = h.v;
    }
    if (tg < K) {
        const float4* c = (const float4*)(cb + (size_t)tg * D);
        float s0 = 0.f, s1 = 0.f, s2 = 0.f, s3 = 0.f;
#pragma unroll
        for (int i = 0; i < D / 4; ++i) {
            float4 v = c[i];
            s0 = fmaf(v.x, v.x, s0);
            s1 = fmaf(v.y, v.y, s1);
            s2 = fmaf(v.z, v.z, s2);
            s3 = fmaf(v.w, v.w, s3);
        }
        cnorm[tg] = (s0 + s1) + (s2 + s3);
    }
}

// issue one 16B load: un-sinkable (volatile), SGPR base + 32b voffset + imm
#define GL(dst, voff, imm)                                             \
    asm volatile("global_load_dwordx4 %0, %1, %2 offset:" #imm        \
                 : "=v"(dst) : "v"(voff), "s"(cbh))

#define ISSUE_A() do {                                                 \
    GL(a0, vA0, 0); GL(a1, vA0, 1024); GL(a2, vA0, 2048); GL(a3, vA0, 3072); \
    GL(a4, vA1, 0); GL(a5, vA1, 1024); GL(a6, vA1, 2048); GL(a7, vA1, 3072); \
    vA0 += 16384; vA1 += 16384; } while (0)

#define ISSUE_B() do {                                                 \
    GL(b0, vB0, 0); GL(b1, vB0, 1024); GL(b2, vB0, 2048); GL(b3, vB0, 3072); \
    GL(b4, vB1, 0); GL(b5, vB1, 1024); GL(b6, vB1, 2048); GL(b7, vB1, 3072); \
    vB0 += 16384; vB1 += 16384; } while (0)

// counted wait: N loads may stay in flight; fence MFMA hoisting (rule #18)
#define WAITV(n) do {                                                  \
    asm volatile("s_waitcnt vmcnt(" #n ")" ::: "memory");              \
    __builtin_amdgcn_sched_barrier(0); } while (0)

#define MFMA(A, B, C) __builtin_amdgcn_mfma_f32_16x16x32_bf16(A, B, C, 0, 0, 0)

// one 32-code tile: 16 MFMA (4 chains), lane-local epilogue, register row-min
#define COMPUTE(F0, F1, F2, F3, F4, F5, F6, F7, t) do {                \
    const int cbase = khw * 512 + (t) * 32;                            \
    const f32x4 c0 = *(const f32x4*)&cns[cbase + kg * 4];              \
    const f32x4 c1 = *(const f32x4*)&cns[cbase + 16 + kg * 4];         \
    f32x4 q00 = c0, q01 = c1, q10 = c0, q11 = c1;                      \
    q00 = MFMA(F0, xb0[0], q00); q10 = MFMA(F0, xb1[0], q10);          \
    q01 = MFMA(F4, xb0[0], q01); q11 = MFMA(F4, xb1[0], q11);          \
    q00 = MFMA(F1, xb0[1], q00); q10 = MFMA(F1, xb1[1], q10);          \
    q01 = MFMA(F5, xb0[1], q01); q11 = MFMA(F5, xb1[1], q11);          \
    q00 = MFMA(F2, xb0[2], q00); q10 = MFMA(F2, xb1[2], q10);          \
    q01 = MFMA(F6, xb0[2], q01); q11 = MFMA(F6, xb1[2], q11);          \
    q00 = MFMA(F3, xb0[3], q00); q10 = MFMA(F3, xb1[3], q10);          \
    q01 = MFMA(F7, xb0[3], q01); q11 = MFMA(F7, xb1[3], q11);          \
    float m0 = fminf(fminf(fminf(q00[0], q00[1]), fminf(q00[2], q00[3])),  \
                     fminf(fminf(q01[0], q01[1]), fminf(q01[2], q01[3]))); \
    float m1 = fminf(fminf(fminf(q10[0], q10[1]), fminf(q10[2], q10[3])),  \
                     fminf(fminf(q11[0], q11[1]), fminf(q11[2], q11[3]))); \
    m0 = fminf(m0, __shfl_xor(m0, 16)); m0 = fminf(m0, __shfl_xor(m0, 32)); \
    m1 = fminf(m1, __shfl_xor(m1, 16)); m1 = fminf(m1, __shfl_xor(m1, 32)); \
    if (__any((m0 < rm0 + MARGIN) | (m1 < rm1 + MARGIN))) {            \
        const float th0 = fminf(rm0, m0) + MARGIN;                     \
        const float th1 = fminf(rm1, m1) + MARGIN;                     \
        const int rA = rg * 32 + la, rB = rA + 16;                     \
        _Pragma("unroll")                                              \
        for (int i = 0; i < 4; ++i) {                                  \
            if (q00[i] < th0) { int p = atomicAdd(&ccnt, 1);           \
                if (p < LCAP) clist[p] = (unsigned)((rA << 10) | (cbase + kg * 4 + i)); } \
            if (q01[i] < th0) { int p = atomicAdd(&ccnt, 1);           \
                if (p < LCAP) clist[p] = (unsigned)((rA << 10) | (cbase + 16 + kg * 4 + i)); } \
            if (q10[i] < th1) { int p = atomicAdd(&ccnt, 1);           \
                if (p < LCAP) clist[p] = (unsigned)((rB << 10) | (cbase + kg * 4 + i)); } \
            if (q11[i] < th1) { int p = atomicAdd(&ccnt, 1);           \
                if (p < LCAP) clist[p] = (unsigned)((rB << 10) | (cbase + 16 + kg * 4 + i)); } \
        }                                                              \
    }                                                                  \
    rm0 = fminf(rm0, m0); rm1 = fminf(rm1, m1); } while (0)

__global__ __launch_bounds__(NTH, 2) void vq_mfma(const float* __restrict__ x,
                                                  const float* __restrict__ cb,
                                                  const short* __restrict__ cbh,
                                                  const float* __restrict__ cnorm,
                                                  float* __restrict__ out,
                                                  int N, int K) {
    __shared__ float cns[1024];          // 4 KB
    __shared__ unsigned clist[LCAP];     // 8 KB
    __shared__ unsigned long long win[BR];
    __shared__ int ccnt;

    const int tid = threadIdx.x;
    const int lane = tid & 63;
    const int wv = tid >> 6;   // 0..3
    const int rg = wv >> 1;    // row-group: rows rg*32 .. rg*32+31
    const int khw = wv & 1;    // K half (512 codes) this wave covers
    const int la = lane & 15;
    const int kg = lane >> 4;
    const int row0 = blockIdx.x * BR;

    if (tid < BR) win[tid] = ~0ull;
    if (tid == 0) ccnt = 0;
    for (int i = tid; i < K; i += NTH) cns[i] = cnorm[i];

    // ---- bf16(-2x) B-fragments for TWO 16-row groups (col=la=row, k=kg*8+j) ----
    bfrag xb0[4], xb1[4];
    {
        const float* xp0 = x + (size_t)(row0 + rg * 32 + la) * D + kg * 8;
        const float* xp1 = xp0 + 16 * D;
#pragma unroll
        for (int ks = 0; ks < 4; ++ks) {
            float4 f0 = *(const float4*)(xp0 + ks * 32);
            float4 f1 = *(const float4*)(xp0 + ks * 32 + 4);
            FU h;
            h.u[0] = cvtpk(-2.f * f0.x, -2.f * f0.y);
            h.u[1] = cvtpk(-2.f * f0.z, -2.f * f0.w);
            h.u[2] = cvtpk(-2.f * f1.x, -2.f * f1.y);
            h.u[3] = cvtpk(-2.f * f1.z, -2.f * f1.w);
            xb0[ks] = h.v;
            f0 = *(const float4*)(xp1 + ks * 32);
            f1 = *(const float4*)(xp1 + ks * 32 + 4);
            h.u[0] = cvtpk(-2.f * f0.x, -2.f * f0.y);
            h.u[1] = cvtpk(-2.f * f0.z, -2.f * f0.w);
            h.u[2] = cvtpk(-2.f * f1.x, -2.f * f1.y);
            h.u[3] = cvtpk(-2.f * f1.z, -2.f * f1.w);
            xb1[ks] = h.v;
        }
    }
    __syncthreads();  // drains vmcnt to 0 (clean counting) + LDS ready

    // per-lane 32-bit voffsets into cbh fragments (SGPR base in the asm)
    unsigned vA0 = (unsigned)(khw * 131072 + lane * 16);
    unsigned vA1 = vA0 + 4096;
    unsigned vB0 = vA0 + 8192;
    unsigned vB1 = vA0 + 12288;
    bfrag a0, a1, a2, a3, a4, a5, a6, a7;
    bfrag b0, b1, b2, b3, b4, b5, b6, b7;
    float rm0 = 3.4e38f, rm1 = 3.4e38f;

    ISSUE_A();  // tile 0 -> vmcnt 8
    ISSUE_B();  // tile 1 -> vmcnt 16

#pragma unroll 1
    for (int it = 0; it < 7; ++it) {
        const int t = 2 * it;
        WAITV(8);   // tile t landed; tile t+1 still in flight
        COMPUTE(a0, a1, a2, a3, a4, a5, a6, a7, t);
        ISSUE_A();  // tile t+2
        WAITV(8);   // tile t+1 landed; tile t+2 in flight
        COMPUTE(b0, b1, b2, b3, b4, b5, b6, b7, t + 1);
        ISSUE_B();  // tile t+3
    }
    WAITV(8);
    COMPUTE(a0, a1, a2, a3, a4, a5, a6, a7, 14);
    WAITV(0);
    COMPUTE(b0, b1, b2, b3, b4, b5, b6, b7, 15);

    __syncthreads();  // all appends visible

    // ---- exact fp32 recheck; packed LDS atomicMin keeps lowest idx on ties ----
    const int nc = (ccnt > LCAP) ? LCAP : ccnt;
    for (int b = wv * 4 + kg; b < nc; b += 16) {  // one candidate per 16-lane group
        const unsigned e = clist[b];
        const int crow = e >> 10, code = e & 1023;
        const float4* xr4 = (const float4*)(x + (size_t)(row0 + crow) * D + la * 8);
        const float4* cr4 = (const float4*)(cb + (size_t)code * D + la * 8);
        float4 p0 = xr4[0], p1 = xr4[1], q0 = cr4[0], q1 = cr4[1];
        float s = p0.x * q0.x;
        s = fmaf(p0.y, q0.y, s); s = fmaf(p0.z, q0.z, s); s = fmaf(p0.w, q0.w, s);
        s = fmaf(p1.x, q1.x, s); s = fmaf(p1.y, q1.y, s);
        s = fmaf(p1.z, q1.z, s); s = fmaf(p1.w, q1.w, s);
#pragma unroll
        for (int off = 1; off <= 8; off <<= 1) s += __shfl_xor(s, off);
        const float dist = fmaf(-2.f, s, cns[code]);
        if (la == 0)
            atomicMin(&win[crow],
                      ((unsigned long long)fenc(dist) << 32) | (unsigned)code);
    }
    __syncthreads();

    // ---- gather: out[row] = cb[winner] (coalesced float4) ----
    {
        const int r = tid >> 2, q = tid & 3;  // 64 rows x 4 chunks of 32 floats
        const int idx = (int)(win[r] & 0xFFFFFFFFull);
        const float4* cs = (const float4*)(cb + (size_t)idx * D + q * 32);
        float4* od = (float4*)(out + (size_t)(row0 + r) * D + q * 32);
#pragma unroll
        for (int i = 0; i < 8; ++i) od[i] = cs[i];
    }
}

extern "C" void kernel_launch(void* const* d_in, const int* in_sizes, int n_in,
                              void* d_out, int out_size, void* d_ws, size_t ws_size,
                              hipStream_t stream) {
    const float* x = (const float*)d_in[0];
    const float* cb = (const float*)d_in[1];
    float* out = (float*)d_out;
    const int N = in_sizes[0] / D;   // 32768
    const int K = in_sizes[1] / D;   // 1024

    float* cnorm = (float*)d_ws;                   // 4 KB
    short* cbh = (short*)((char*)d_ws + 4096);     // 256 KB bf16 fragments

    hipLaunchKernelGGL(prep_kernel, dim3(K * 16 / 256), dim3(256), 0, stream,
                       cb, cnorm, cbh, K);
    hipLaunchKernelGGL(vq_mfma, dim3(N / BR), dim3(NTH), 0, stream,
                       x, cb, cbh, cnorm, out, N, K);
}

// Round 13
// 49.674 us; speedup vs baseline: 1.1997x; 1.1997x over previous
//
#include <hip/hip_runtime.h>

// ResidualVQ forward: out[n] = codebook[argmin_k(-2 x.c_k + ||c_k||^2)]
// v13 = v11 + per-block TILE-PHASE STAGGER (single-variable experiment).
// Theory: all blocks sweeping the 256KB codebook in identical tile order
// serializes on a few L2 slices (same-line hotspot). Staggering the start
// tile per block spreads concurrent reads over all 16 tiles' lines.
// rm/margin logic is order-independent, so correctness proof unchanged.

typedef short bfrag __attribute__((ext_vector_type(8)));  // 8 bf16 = 4 VGPR
typedef float f32x4 __attribute__((ext_vector_type(4)));

constexpr int D = 128;      // embedding dim
constexpr int BR = 32;      // rows per block -> grid 1024 = 4 blocks/CU
constexpr int NTH = 256;    // 4 waves: 2 row-groups (16 rows) x 2 K-halves
constexpr int LCAP = 1024;  // candidate capacity per block
#define MARGIN 3.25f        // > 2 * max |approx dist err| (x split; cb bf16)

__device__ __forceinline__ unsigned fenc(float f) {  // order-preserving f32->u32
    unsigned u = __float_as_uint(f);
    return (u & 0x80000000u) ? ~u : (u | 0x80000000u);
}
__device__ __forceinline__ unsigned cvtpk(float a, float b) {
    unsigned r;
    asm("v_cvt_pk_bf16_f32 %0, %1, %2" : "=v"(r) : "v"(a), "v"(b));
    return r;
}
union FU { bfrag v; unsigned u[4]; };

// 8 fp32 -> bf16 hi fragment + bf16 lo (residual) fragment
__device__ __forceinline__ void conv8(const float* f, bfrag& hi, bfrag& lo) {
    FU h, l;
#pragma unroll
    for (int m = 0; m < 4; ++m) {
        float a = f[2 * m], b = f[2 * m + 1];
        unsigned hp = cvtpk(a, b);
        float ra = a - __uint_as_float(hp << 16);
        float rb = b - __uint_as_float(hp & 0xFFFF0000u);
        h.u[m] = hp;
        l.u[m] = cvtpk(ra, rb);
    }
    hi = h.v;
    lo = l.v;
}

// --- prep: exact cnorm (K threads) + bf16 fragment cast (K*16 threads) ---
__global__ __launch_bounds__(256) void prep_kernel(const float* __restrict__ cb,
                                                   float* __restrict__ cnorm,
                                                   short* __restrict__ hi, int K) {
    const int tg = blockIdx.x * 256 + threadIdx.x;  // 0..16383
    {
        const int cg = tg >> 8;
        const int r = tg & 255;
        const int ks = r >> 6;
        const int lane = r & 63;
        const int kg = lane >> 4, la = lane & 15;
        const float* src = cb + (size_t)(cg * 16 + la) * D + ks * 32 + kg * 8;
        float4 f0 = *(const float4*)src;
        float4 f1 = *(const float4*)(src + 4);
        FU h;
        h.u[0] = cvtpk(f0.x, f0.y);
        h.u[1] = cvtpk(f0.z, f0.w);
        h.u[2] = cvtpk(f1.x, f1.y);
        h.u[3] = cvtpk(f1.z, f1.w);
        ((bfrag*)hi)[tg] = h.v;
    }
    if (tg < K) {
        const float4* c = (const float4*)(cb + (size_t)tg * D);
        float s0 = 0.f, s1 = 0.f, s2 = 0.f, s3 = 0.f;
#pragma unroll
        for (int i = 0; i < D / 4; ++i) {
            float4 v = c[i];
            s0 = fmaf(v.x, v.x, s0);
            s1 = fmaf(v.y, v.y, s1);
            s2 = fmaf(v.z, v.z, s2);
            s3 = fmaf(v.w, v.w, s3);
        }
        cnorm[tg] = (s0 + s1) + (s2 + s3);
    }
}

__global__ __launch_bounds__(NTH, 4) void vq_mfma(const float* __restrict__ x,
                                                  const float* __restrict__ cb,
                                                  const short* __restrict__ cbh,
                                                  const float* __restrict__ cnorm,
                                                  float* __restrict__ out,
                                                  int N, int K) {
    __shared__ float cns[1024];          // 4 KB
    __shared__ unsigned clist[LCAP];     // 4 KB
    __shared__ unsigned long long win[BR];
    __shared__ int ccnt;

    const int tid = threadIdx.x;
    const int lane = tid & 63;
    const int wv = tid >> 6;   // 0..3
    const int rg = wv >> 1;    // row-group (16 rows)
    const int khw = wv & 1;    // K half (512 codes) this wave covers
    const int la = lane & 15;
    const int kg = lane >> 4;
    const int row0 = blockIdx.x * BR;

    // per-block tile phase: nonlinear hash so co-resident blocks (blockIdx
    // differing by multiples of 16) get different phases.
    const int phase = (int)((blockIdx.x * 0x9E3779B1u) >> 24) & 15;

    if (tid < BR) win[tid] = ~0ull;
    if (tid == 0) ccnt = 0;
    for (int i = tid; i < K; i += NTH) cns[i] = cnorm[i];

    // ---- (-2x) -> split-bf16 B-fragments in registers (col=la=row, k=kg*8+j) ----
    bfrag xh[4], xl[4];
    {
        const int xrow = row0 + rg * 16 + la;
        const float* xp = x + (size_t)xrow * D + kg * 8;
#pragma unroll
        for (int ks = 0; ks < 4; ++ks) {
            float4 f0 = *(const float4*)(xp + ks * 32);
            float4 f1 = *(const float4*)(xp + ks * 32 + 4);
            float v[8] = {-2.f * f0.x, -2.f * f0.y, -2.f * f0.z, -2.f * f0.w,
                          -2.f * f1.x, -2.f * f1.y, -2.f * f1.z, -2.f * f1.w};
            conv8(v, xh[ks], xl[ks]);
        }
    }
    __syncthreads();  // ccnt/win/cns ready before any appends

    // per-lane fragment pointer for this wave's K half (L2-resident, 256 KB)
    const bfrag* fpb = (const bfrag*)cbh + (size_t)khw * 8192 + lane;
    const int row = rg * 16 + la;  // block-local row this lane owns
    float rm = 3.4e38f;            // running approx row-min (REGISTER)

    auto load8 = [&](bfrag* dst, int tp) {  // tp = physical tile index
        const bfrag* p = fpb + tp * 512;
#pragma unroll
        for (int cf = 0; cf < 2; ++cf)
#pragma unroll
            for (int ks = 0; ks < 4; ++ks)
                dst[cf * 4 + ks] = p[cf * 256 + ks * 64];  // global_load_dwordx4
    };

    auto compute = [&](const bfrag* f, int tp) {  // one 32-code tile (physical)
        const int cbase = khw * 512 + tp * 32;
        f32x4 acc[2];
        acc[0] = *(const f32x4*)&cns[cbase + kg * 4];        // cn folded in
        acc[1] = *(const f32x4*)&cns[cbase + 16 + kg * 4];
#pragma unroll
        for (int ks = 0; ks < 4; ++ks)
#pragma unroll
            for (int cf = 0; cf < 2; ++cf) {
                // swapped operands: A=codebook, B=x -> C[row=code][col=x-row]
                acc[cf] = __builtin_amdgcn_mfma_f32_16x16x32_bf16(
                    f[cf * 4 + ks], xh[ks], acc[cf], 0, 0, 0);
                acc[cf] = __builtin_amdgcn_mfma_f32_16x16x32_bf16(
                    f[cf * 4 + ks], xl[ks], acc[cf], 0, 0, 0);
            }
        // acc[cf][i] = dist(code cbase+cf*16+kg*4+i, row)
        float m = fminf(fminf(fminf(acc[0][0], acc[0][1]), fminf(acc[0][2], acc[0][3])),
                        fminf(fminf(acc[1][0], acc[1][1]), fminf(acc[1][2], acc[1][3])));
        m = fminf(m, __shfl_xor(m, 16));
        m = fminf(m, __shfl_xor(m, 32));  // min over this tile's 32 codes for `row`
        // append only when the tile approaches the running min (order-free proof:
        // at the winner's tile, approx(w) <= rm + 2e < rm + MARGIN regardless of
        // visit order; fmin(rm, m) bounds the first tile (rm = +inf)).
        if (__any(m < rm + MARGIN)) {
            const float thr = fminf(rm, m) + MARGIN;
#pragma unroll
            for (int cf = 0; cf < 2; ++cf)
#pragma unroll
                for (int i = 0; i < 4; ++i) {
                    if (acc[cf][i] < thr) {
                        int p = atomicAdd(&ccnt, 1);
                        if (p < LCAP)
                            clist[p] = (unsigned)((row << 10)
                                                  | (cbase + cf * 16 + kg * 4 + i));
                    }
                }
        }
        rm = fminf(rm, m);
    };

    // ---- barrier-free K-loop: 16 tiles, staggered start, reg double-buffer ----
    bfrag cur[8], nxt[8];
    load8(cur, phase);
#pragma unroll 1
    for (int t = 0; t < 16; t += 2) {
        load8(nxt, (t + 1 + phase) & 15);   // in flight under compute(cur)
        compute(cur, (t + phase) & 15);
        if (t + 2 < 16) load8(cur, (t + 2 + phase) & 15);
        compute(nxt, (t + 1 + phase) & 15);
    }

    __syncthreads();  // all appends visible

    // ---- exact fp32 recheck; packed LDS atomicMin keeps lowest idx on ties ----
    const int nc = (ccnt > LCAP) ? LCAP : ccnt;
    for (int b = wv * 4 + kg; b < nc; b += 16) {  // one candidate per 16-lane group
        const unsigned e = clist[b];
        const int crow = e >> 10, code = e & 1023;
        const float4* xr4 = (const float4*)(x + (size_t)(row0 + crow) * D + la * 8);
        const float4* cr4 = (const float4*)(cb + (size_t)code * D + la * 8);
        float4 a0 = xr4[0], a1 = xr4[1], b0 = cr4[0], b1 = cr4[1];
        float s = a0.x * b0.x;
        s = fmaf(a0.y, b0.y, s); s = fmaf(a0.z, b0.z, s); s = fmaf(a0.w, b0.w, s);
        s = fmaf(a1.x, b1.x, s); s = fmaf(a1.y, b1.y, s);
        s = fmaf(a1.z, b1.z, s); s = fmaf(a1.w, b1.w, s);
#pragma unroll
        for (int off = 1; off <= 8; off <<= 1) s += __shfl_xor(s, off);
        const float dist = fmaf(-2.f, s, cns[code]);
        if (la == 0)
            atomicMin(&win[crow],
                      ((unsigned long long)fenc(dist) << 32) | (unsigned)code);
    }
    __syncthreads();

    // ---- gather: out[row] = cb[winner] (coalesced float4) ----
    {
        const int r = tid >> 3, q = tid & 7;  // 32 rows x 8 chunks of 16 floats
        const int idx = (int)(win[r] & 0xFFFFFFFFull);
        const float4* cs = (const float4*)(cb + (size_t)idx * D + q * 16);
        float4* od = (float4*)(out + (size_t)(row0 + r) * D + q * 16);
#pragma unroll
        for (int i = 0; i < 4; ++i) od[i] = cs[i];
    }
}

extern "C" void kernel_launch(void* const* d_in, const int* in_sizes, int n_in,
                              void* d_out, int out_size, void* d_ws, size_t ws_size,
                              hipStream_t stream) {
    const float* x = (const float*)d_in[0];
    const float* cb = (const float*)d_in[1];
    float* out = (float*)d_out;
    const int N = in_sizes[0] / D;   // 32768
    const int K = in_sizes[1] / D;   // 1024

    float* cnorm = (float*)d_ws;                   // 4 KB
    short* cbh = (short*)((char*)d_ws + 4096);     // 256 KB bf16 fragments

    hipLaunchKernelGGL(prep_kernel, dim3(K * 16 / 256), dim3(256), 0, stream,
                       cb, cnorm, cbh, K);
    hipLaunchKernelGGL(vq_mfma, dim3(N / BR), dim3(NTH), 0, stream,
                       x, cb, cbh, cnorm, out, N, K);
}